// Round 8
// baseline (178.557 us; speedup 1.0000x reference)
//
#include <hip/hip_runtime.h>
#include <hip/hip_bf16.h>

// Problem constants
#define BSZ   4096
#define NOBJ  16
#define DOBS  256
#define ADIM  4
#define HID   512
#define KP1   288   // node_in (260) padded to multiple of 32 for MFMA K-loop

#define MB    8     // batch rows per block (grid = 512 -> 2 blocks/CU)
#define NT    512   // threads per block (8 waves)
#define XP1   296   // xbar LDS row stride (u16): 592B
#define HP    520   // h1/h2 LDS row stride (u16): 1040B
#define TP    260   // t3 LDS row stride (f32): 1040B

typedef unsigned short u16;
typedef __bf16 bf16x8 __attribute__((ext_vector_type(8)));
typedef float  f32x4  __attribute__((ext_vector_type(4)));
typedef unsigned short u16x8 __attribute__((ext_vector_type(8)));
typedef unsigned short u16x4 __attribute__((ext_vector_type(4)));

static __device__ __forceinline__ u16 f2bf(float f) {
    __hip_bfloat16 h = __float2bfloat16(f);
    return __builtin_bit_cast(u16, h);
}
static __device__ __forceinline__ bf16x8 ldg8(const u16* p) {
    return __builtin_bit_cast(bf16x8, *(const u16x8*)p);
}

// ---------------------------------------------------------------------------
// K0: transpose + cast weights to bf16, stored as W^T[N][K].
// ---------------------------------------------------------------------------
__global__ void prep_weights(const float* __restrict__ W1, const float* __restrict__ W2,
                             const float* __restrict__ W3,
                             u16* __restrict__ W1T, u16* __restrict__ W2T, u16* __restrict__ W3T) {
    int idx = blockIdx.x * 256 + threadIdx.x;
    const int n1 = HID * KP1;      // 147456
    const int n2 = HID * HID;      // 262144
    const int n3 = DOBS * HID;     // 131072
    if (idx < n1) {
        int h = idx / KP1, k = idx % KP1;
        float v = (k < DOBS + ADIM) ? W1[k * HID + h] : 0.0f;
        W1T[idx] = f2bf(v);
    } else if (idx < n1 + n2) {
        int t = idx - n1;
        int h = t / HID, k = t % HID;
        W2T[t] = f2bf(W2[k * HID + h]);
    } else if (idx < n1 + n2 + n3) {
        int t = idx - n1 - n2;
        int n = t / HID, k = t % HID;
        W3T[t] = f2bf(W3[k * DOBS + n]);
    }
}

// ---------------------------------------------------------------------------
// Fused per-row MLP, 8 waves / 512 threads, 8 batch rows/block, 2 blocks/CU.
// GEMM1/2: wave w owns N-cols [w*64,(w+1)*64); GEMM3: [w*32,(w+1)*32).
// MFMA rows 8-15 are garbage (uninit LDS, finite) and masked at C-writes
// (lg<2 guard). mfma_f32_16x16x32_bf16: A lane l: row l&15, k=8*(l>>4)+j;
// B lane l: col l&15; D: col=l&15, row=4*(l>>4)+r. (verified rounds 2/6/7)
// ---------------------------------------------------------------------------
__global__ __launch_bounds__(NT, 4) void fused_mlp(
    const float* __restrict__ states, const int* __restrict__ action,
    const u16* __restrict__ W1T, const float* __restrict__ b1,
    const u16* __restrict__ W2T, const float* __restrict__ b2,
    const u16* __restrict__ W3T, const float* __restrict__ b3,
    const float* __restrict__ lng, const float* __restrict__ lnb,
    float* __restrict__ out)
{
    __shared__ u16   xbar[16][XP1];   // rows >= MB uninitialized (finite)
    __shared__ u16   h1[16][HP];
    __shared__ u16   h2[16][HP];
    __shared__ float t3[MB][TP];
    __shared__ float red[2][8][16];

    const int t  = threadIdx.x;
    const int w  = t >> 6;
    const int l  = t & 63;
    const int lr = l & 15;
    const int lg = l >> 4;
    const int b0 = blockIdx.x * MB;

    // ---- Phase 0: mean over 16 objects, float4; one thread per (r,d4) ----
    {
        const float4* sf4 = (const float4*)states;   // [B][16][64] float4
        int r = t >> 6, d4 = t & 63;                 // 512 = 8 x 64 exact
        float sx = 0.f, sy = 0.f, sz = 0.f, sw = 0.f;
        const float4* rp = sf4 + (((size_t)(b0 + r) * NOBJ) << 6) + d4;
        #pragma unroll
        for (int o = 0; o < NOBJ; ++o) {
            float4 v = rp[o << 6];
            sx += v.x; sy += v.y; sz += v.z; sw += v.w;
        }
        u16x4 st = { f2bf(sx * (1.0f / NOBJ)), f2bf(sy * (1.0f / NOBJ)),
                     f2bf(sz * (1.0f / NOBJ)), f2bf(sw * (1.0f / NOBJ)) };
        *(u16x4*)&xbar[r][d4 * 4] = st;
        if (t < MB) {
            int a = action[b0 + t] & 3;
            #pragma unroll
            for (int k = 0; k < KP1 - DOBS; ++k)
                xbar[t][DOBS + k] = f2bf(k == a ? (1.0f / NOBJ) : 0.0f);
        }
    }
    __syncthreads();

    // ---- Phase 1: h1 = relu(xbar @ W1 + b1); wave cols [w*64, w*64+64) ----
    {
        f32x4 acc[4] = {};
        #pragma unroll 3
        for (int ks = 0; ks < KP1 / 32; ++ks) {
            bf16x8 a = ldg8(&xbar[lr][ks * 32 + lg * 8]);
            #pragma unroll
            for (int nb = 0; nb < 4; ++nb) {
                int n = w * 64 + nb * 16 + lr;
                bf16x8 bv = ldg8(W1T + (size_t)n * KP1 + ks * 32 + lg * 8);
                acc[nb] = __builtin_amdgcn_mfma_f32_16x16x32_bf16(a, bv, acc[nb], 0, 0, 0);
            }
        }
        if (lg < 2) {   // rows lg*4+r in [0,8)
            #pragma unroll
            for (int nb = 0; nb < 4; ++nb) {
                int n = w * 64 + nb * 16 + lr;
                float bias = b1[n];
                #pragma unroll
                for (int r = 0; r < 4; ++r)
                    h1[lg * 4 + r][n] = f2bf(fmaxf(acc[nb][r] + bias, 0.f));
            }
        }
    }
    __syncthreads();

    // ---- Phase 2: t2 = h1 @ W2 + b2 (regs); LN + relu -> h2 ----
    {
        f32x4 acc[4] = {};
        #pragma unroll 4
        for (int ks = 0; ks < HID / 32; ++ks) {
            bf16x8 a = ldg8(&h1[lr][ks * 32 + lg * 8]);
            #pragma unroll
            for (int nb = 0; nb < 4; ++nb) {
                int n = w * 64 + nb * 16 + lr;
                bf16x8 bv = ldg8(W2T + (size_t)n * HID + ks * 32 + lg * 8);
                acc[nb] = __builtin_amdgcn_mfma_f32_16x16x32_bf16(a, bv, acc[nb], 0, 0, 0);
            }
        }
        float s1[4] = {0.f, 0.f, 0.f, 0.f}, s2[4] = {0.f, 0.f, 0.f, 0.f};
        #pragma unroll
        for (int nb = 0; nb < 4; ++nb) {
            float bias = b2[w * 64 + nb * 16 + lr];
            #pragma unroll
            for (int r = 0; r < 4; ++r) {
                float v = acc[nb][r] + bias;
                acc[nb][r] = v;
                s1[r] += v;
                s2[r] += v * v;
            }
        }
        #pragma unroll
        for (int r = 0; r < 4; ++r) {
            #pragma unroll
            for (int m = 8; m; m >>= 1) {      // reduce over lr bits
                s1[r] += __shfl_xor(s1[r], m, 64);
                s2[r] += __shfl_xor(s2[r], m, 64);
            }
            if (lr == 0) {
                red[0][w][lg * 4 + r] = s1[r];
                red[1][w][lg * 4 + r] = s2[r];
            }
        }
        __syncthreads();
        float muv[4], rsv[4];
        #pragma unroll
        for (int r = 0; r < 4; ++r) {
            int m = lg * 4 + r;
            float S1 = 0.f, S2 = 0.f;
            #pragma unroll
            for (int ww = 0; ww < 8; ++ww) { S1 += red[0][ww][m]; S2 += red[1][ww][m]; }
            float mu = S1 * (1.0f / HID);
            float var = S2 * (1.0f / HID) - mu * mu;
            muv[r] = mu;
            rsv[r] = rsqrtf(var + 1e-5f);       // garbage rows may be NaN; never stored
        }
        if (lg < 2) {
            #pragma unroll
            for (int nb = 0; nb < 4; ++nb) {
                int n = w * 64 + nb * 16 + lr;
                float g = lng[n], bb = lnb[n];
                #pragma unroll
                for (int r = 0; r < 4; ++r) {
                    float y = (acc[nb][r] - muv[r]) * rsv[r] * g + bb;
                    h2[lg * 4 + r][n] = f2bf(fmaxf(y, 0.f));
                }
            }
        }
    }
    __syncthreads();

    // ---- Phase 3: t3 = h2 @ W3 + b3; wave cols [w*32, w*32+32) ----
    {
        f32x4 acc[2] = {};
        #pragma unroll 4
        for (int ks = 0; ks < HID / 32; ++ks) {
            bf16x8 a = ldg8(&h2[lr][ks * 32 + lg * 8]);
            #pragma unroll
            for (int nb = 0; nb < 2; ++nb) {
                int n = w * 32 + nb * 16 + lr;
                bf16x8 bv = ldg8(W3T + (size_t)n * HID + ks * 32 + lg * 8);
                acc[nb] = __builtin_amdgcn_mfma_f32_16x16x32_bf16(a, bv, acc[nb], 0, 0, 0);
            }
        }
        if (lg < 2) {
            #pragma unroll
            for (int nb = 0; nb < 2; ++nb) {
                int n = w * 32 + nb * 16 + lr;
                float bias = b3[n];
                #pragma unroll
                for (int r = 0; r < 4; ++r)
                    t3[lg * 4 + r][n] = acc[nb][r] + bias;
            }
        }
    }
    __syncthreads();

    // ---- Phase 4: broadcast-store out[b][o][:] = t3[b][:], float4 ----
    {
        #pragma unroll 8
        for (int i = 0; i < 16; ++i) {
            int flat = i * NT + t;           // [r:8][o:16][d4:64] float4
            int d4 = flat & 63;
            int o  = (flat >> 6) & 15;
            int r  = flat >> 10;
            float4 v = *(const float4*)&t3[r][d4 * 4];
            *(float4*)(out + ((size_t)(b0 + r) * NOBJ + o) * DOBS + d4 * 4) = v;
        }
    }
}

// ---------------------------------------------------------------------------
extern "C" void kernel_launch(void* const* d_in, const int* in_sizes, int n_in,
                              void* d_out, int out_size, void* d_ws, size_t ws_size,
                              hipStream_t stream) {
    const float* states = (const float*)d_in[0];
    const int*   action = (const int*)d_in[1];
    const float* W1 = (const float*)d_in[2];
    const float* b1 = (const float*)d_in[3];
    const float* W2 = (const float*)d_in[4];
    const float* b2 = (const float*)d_in[5];
    const float* W3 = (const float*)d_in[6];
    const float* b3 = (const float*)d_in[7];
    const float* lng = (const float*)d_in[8];
    const float* lnb = (const float*)d_in[9];
    float* out = (float*)d_out;

    char* ws = (char*)d_ws;
    size_t off = 0;
    auto alloc = [&](size_t bytes) -> void* {
        void* p = ws + off;
        off = (off + bytes + 255) & ~(size_t)255;
        return p;
    };
    u16* W1T = (u16*)alloc((size_t)HID * KP1 * 2);
    u16* W2T = (u16*)alloc((size_t)HID * HID * 2);
    u16* W3T = (u16*)alloc((size_t)DOBS * HID * 2);

    prep_weights<<<2112, 256, 0, stream>>>(W1, W2, W3, W1T, W2T, W3T);
    fused_mlp<<<BSZ / MB, NT, 0, stream>>>(states, action,
                                           W1T, b1, W2T, b2, W3T, b3,
                                           lng, lnb, out);
}

// Round 10
// 157.843 us; speedup vs baseline: 1.1312x; 1.1312x over previous
//
#include <hip/hip_runtime.h>
#include <hip/hip_bf16.h>

// Problem constants
#define BSZ   4096
#define NOBJ  16
#define DOBS  256
#define ADIM  4
#define HID   512
#define KP1   288   // node_in (260) padded to multiple of 32 for MFMA K-loop

#define MB    16    // batch rows per block (grid = 256 -> 1 block/CU)
#define NT    512   // threads per block (8 waves)
#define XP1   296   // xbar LDS row stride (u16): 592B
#define HP    520   // h1/h2 LDS row stride (u16): 1040B
#define TP    260   // t3 LDS row stride (f32): 1040B

typedef unsigned short u16;
typedef __bf16 bf16x8 __attribute__((ext_vector_type(8)));
typedef float  f32x4  __attribute__((ext_vector_type(4)));
typedef unsigned short u16x8 __attribute__((ext_vector_type(8)));
typedef unsigned short u16x4 __attribute__((ext_vector_type(4)));

static __device__ __forceinline__ u16 f2bf(float f) {
    __hip_bfloat16 h = __float2bfloat16(f);
    return __builtin_bit_cast(u16, h);
}
static __device__ __forceinline__ bf16x8 ldg8(const u16* p) {
    return __builtin_bit_cast(bf16x8, *(const u16x8*)p);
}

// ---------------------------------------------------------------------------
// K0: weight transpose+cast via LDS 32x32 tiles (round-8 fix: the old version
// read W[k*H+h] at 2KB stride, uncoalesced -> ~90us. Now: coalesced f32 reads
// (consecutive h per lane), coalesced bf16 writes (consecutive k per lane)).
// W1 [260][512] -> W1T[512][288] (k-pad 0); W2 [512][512] -> W2T[512][512];
// W3 [512][256] -> W3T[256][512].
// ---------------------------------------------------------------------------
__global__ __launch_bounds__(256) void prep_weights(
    const float* __restrict__ W1, const float* __restrict__ W2,
    const float* __restrict__ W3,
    u16* __restrict__ W1T, u16* __restrict__ W2T, u16* __restrict__ W3T) {
    int bid = blockIdx.x;
    const float* src; u16* dst; int Ksrc, H, Kp, tk, th;
    if (bid < 144)      { src = W1; dst = W1T; Ksrc = 260; H = 512; Kp = 288; tk = bid / 16;        th = bid % 16; }
    else if (bid < 400) { src = W2; dst = W2T; Ksrc = 512; H = 512; Kp = 512; tk = (bid-144) / 16;  th = (bid-144) % 16; }
    else                { src = W3; dst = W3T; Ksrc = 512; H = 256; Kp = 512; tk = (bid-400) / 8;   th = (bid-400) % 8; }

    __shared__ float tile[32][33];
    int tx = threadIdx.x & 31, ty = threadIdx.x >> 5;   // 32 x 8
    #pragma unroll
    for (int i = 0; i < 4; ++i) {
        int k = tk * 32 + ty + i * 8;
        int h = th * 32 + tx;
        tile[ty + i * 8][tx] = (k < Ksrc) ? src[(size_t)k * H + h] : 0.f;
    }
    __syncthreads();
    #pragma unroll
    for (int i = 0; i < 4; ++i) {
        int h = th * 32 + ty + i * 8;
        int k = tk * 32 + tx;
        dst[(size_t)h * Kp + k] = f2bf(tile[tx][ty + i * 8]);
    }
}

// ---------------------------------------------------------------------------
// Fused per-row MLP, 8 waves / 512 threads per block, 16 batch rows/block.
// (round-7 version, measured 58-65us — reverted after round-8 MB=8 regression)
// GEMM1/2: wave w owns N-cols [w*64,(w+1)*64); GEMM3: [w*32,(w+1)*32).
// mfma_f32_16x16x32_bf16: A lane l: row l&15, k=8*(l>>4)+j; B lane l: col l&15;
// D: col=l&15, row=4*(l>>4)+r.  (verified: rounds 2/6/7)
// ---------------------------------------------------------------------------
__global__ __launch_bounds__(NT) void fused_mlp(
    const float* __restrict__ states, const int* __restrict__ action,
    const u16* __restrict__ W1T, const float* __restrict__ b1,
    const u16* __restrict__ W2T, const float* __restrict__ b2,
    const u16* __restrict__ W3T, const float* __restrict__ b3,
    const float* __restrict__ lng, const float* __restrict__ lnb,
    float* __restrict__ out)
{
    __shared__ u16   xbar[MB][XP1];
    __shared__ u16   h1[MB][HP];
    __shared__ u16   h2[MB][HP];
    __shared__ float t3[MB][TP];
    __shared__ float red[2][8][MB];

    const int t  = threadIdx.x;
    const int w  = t >> 6;
    const int l  = t & 63;
    const int lr = l & 15;
    const int lg = l >> 4;
    const int b0 = blockIdx.x * MB;

    // ---- Phase 0: mean over 16 objects, float4-vectorized ----
    {
        const float4* sf4 = (const float4*)states;  // [4096][16][64] float4
        #pragma unroll
        for (int p = 0; p < 2; ++p) {
            int idx = p * NT + t;            // 0..1023 = [r:16][d4:64]
            int r = idx >> 6, d4 = idx & 63;
            float sx = 0.f, sy = 0.f, sz = 0.f, sw = 0.f;
            const float4* rp = sf4 + (((size_t)(b0 + r) * NOBJ) << 6) + d4;
            #pragma unroll
            for (int o = 0; o < NOBJ; ++o) {
                float4 v = rp[o << 6];
                sx += v.x; sy += v.y; sz += v.z; sw += v.w;
            }
            u16x4 st = { f2bf(sx * (1.0f / NOBJ)), f2bf(sy * (1.0f / NOBJ)),
                         f2bf(sz * (1.0f / NOBJ)), f2bf(sw * (1.0f / NOBJ)) };
            *(u16x4*)&xbar[r][d4 * 4] = st;
        }
        if (t < MB) {
            int a = action[b0 + t] & 3;
            #pragma unroll
            for (int k = 0; k < KP1 - DOBS; ++k)
                xbar[t][DOBS + k] = f2bf(k == a ? (1.0f / NOBJ) : 0.0f);
        }
    }
    __syncthreads();

    // ---- Phase 1: h1 = relu(xbar @ W1 + b1); wave cols [w*64, w*64+64) ----
    {
        f32x4 acc[4] = {};
        #pragma unroll 3
        for (int ks = 0; ks < KP1 / 32; ++ks) {
            bf16x8 a = ldg8(&xbar[lr][ks * 32 + lg * 8]);
            #pragma unroll
            for (int nb = 0; nb < 4; ++nb) {
                int n = w * 64 + nb * 16 + lr;
                bf16x8 bv = ldg8(W1T + (size_t)n * KP1 + ks * 32 + lg * 8);
                acc[nb] = __builtin_amdgcn_mfma_f32_16x16x32_bf16(a, bv, acc[nb], 0, 0, 0);
            }
        }
        #pragma unroll
        for (int nb = 0; nb < 4; ++nb) {
            int n = w * 64 + nb * 16 + lr;
            float bias = b1[n];
            #pragma unroll
            for (int r = 0; r < 4; ++r)
                h1[lg * 4 + r][n] = f2bf(fmaxf(acc[nb][r] + bias, 0.f));
        }
    }
    __syncthreads();

    // ---- Phase 2: t2 = h1 @ W2 + b2 (regs); LN + relu -> h2 ----
    {
        f32x4 acc[4] = {};
        #pragma unroll 4
        for (int ks = 0; ks < HID / 32; ++ks) {
            bf16x8 a = ldg8(&h1[lr][ks * 32 + lg * 8]);
            #pragma unroll
            for (int nb = 0; nb < 4; ++nb) {
                int n = w * 64 + nb * 16 + lr;
                bf16x8 bv = ldg8(W2T + (size_t)n * HID + ks * 32 + lg * 8);
                acc[nb] = __builtin_amdgcn_mfma_f32_16x16x32_bf16(a, bv, acc[nb], 0, 0, 0);
            }
        }
        float s1[4] = {0.f, 0.f, 0.f, 0.f}, s2[4] = {0.f, 0.f, 0.f, 0.f};
        #pragma unroll
        for (int nb = 0; nb < 4; ++nb) {
            float bias = b2[w * 64 + nb * 16 + lr];
            #pragma unroll
            for (int r = 0; r < 4; ++r) {
                float v = acc[nb][r] + bias;
                acc[nb][r] = v;
                s1[r] += v;
                s2[r] += v * v;
            }
        }
        #pragma unroll
        for (int r = 0; r < 4; ++r) {
            #pragma unroll
            for (int m = 8; m; m >>= 1) {      // reduce over lr bits (0..3)
                s1[r] += __shfl_xor(s1[r], m, 64);
                s2[r] += __shfl_xor(s2[r], m, 64);
            }
            if (lr == 0) {
                red[0][w][lg * 4 + r] = s1[r];
                red[1][w][lg * 4 + r] = s2[r];
            }
        }
        __syncthreads();
        float muv[4], rsv[4];
        #pragma unroll
        for (int r = 0; r < 4; ++r) {
            int m = lg * 4 + r;
            float S1 = 0.f, S2 = 0.f;
            #pragma unroll
            for (int ww = 0; ww < 8; ++ww) { S1 += red[0][ww][m]; S2 += red[1][ww][m]; }
            float mu = S1 * (1.0f / HID);
            float var = S2 * (1.0f / HID) - mu * mu;
            muv[r] = mu;
            rsv[r] = rsqrtf(var + 1e-5f);
        }
        #pragma unroll
        for (int nb = 0; nb < 4; ++nb) {
            int n = w * 64 + nb * 16 + lr;
            float g = lng[n], bb = lnb[n];
            #pragma unroll
            for (int r = 0; r < 4; ++r) {
                float y = (acc[nb][r] - muv[r]) * rsv[r] * g + bb;
                h2[lg * 4 + r][n] = f2bf(fmaxf(y, 0.f));
            }
        }
    }
    __syncthreads();

    // ---- Phase 3: t3 = h2 @ W3 + b3; wave cols [w*32, w*32+32) ----
    {
        f32x4 acc[2] = {};
        #pragma unroll 4
        for (int ks = 0; ks < HID / 32; ++ks) {
            bf16x8 a = ldg8(&h2[lr][ks * 32 + lg * 8]);
            #pragma unroll
            for (int nb = 0; nb < 2; ++nb) {
                int n = w * 32 + nb * 16 + lr;
                bf16x8 bv = ldg8(W3T + (size_t)n * HID + ks * 32 + lg * 8);
                acc[nb] = __builtin_amdgcn_mfma_f32_16x16x32_bf16(a, bv, acc[nb], 0, 0, 0);
            }
        }
        #pragma unroll
        for (int nb = 0; nb < 2; ++nb) {
            int n = w * 32 + nb * 16 + lr;
            float bias = b3[n];
            #pragma unroll
            for (int r = 0; r < 4; ++r)
                t3[lg * 4 + r][n] = acc[nb][r] + bias;
        }
    }
    __syncthreads();

    // ---- Phase 4: broadcast-store out[b][o][:] = t3[b][:], float4 ----
    {
        #pragma unroll 8
        for (int i = 0; i < 32; ++i) {
            int flat = i * NT + t;           // [r:16][o:16][d4:64] float4
            int d4 = flat & 63;
            int o  = (flat >> 6) & 15;
            int r  = flat >> 10;
            float4 v = *(const float4*)&t3[r][d4 * 4];
            *(float4*)(out + ((size_t)(b0 + r) * NOBJ + o) * DOBS + d4 * 4) = v;
        }
    }
}

// ---------------------------------------------------------------------------
extern "C" void kernel_launch(void* const* d_in, const int* in_sizes, int n_in,
                              void* d_out, int out_size, void* d_ws, size_t ws_size,
                              hipStream_t stream) {
    const float* states = (const float*)d_in[0];
    const int*   action = (const int*)d_in[1];
    const float* W1 = (const float*)d_in[2];
    const float* b1 = (const float*)d_in[3];
    const float* W2 = (const float*)d_in[4];
    const float* b2 = (const float*)d_in[5];
    const float* W3 = (const float*)d_in[6];
    const float* b3 = (const float*)d_in[7];
    const float* lng = (const float*)d_in[8];
    const float* lnb = (const float*)d_in[9];
    float* out = (float*)d_out;

    char* ws = (char*)d_ws;
    size_t off = 0;
    auto alloc = [&](size_t bytes) -> void* {
        void* p = ws + off;
        off = (off + bytes + 255) & ~(size_t)255;
        return p;
    };
    u16* W1T = (u16*)alloc((size_t)HID * KP1 * 2);
    u16* W2T = (u16*)alloc((size_t)HID * HID * 2);
    u16* W3T = (u16*)alloc((size_t)DOBS * HID * 2);

    prep_weights<<<528, 256, 0, stream>>>(W1, W2, W3, W1T, W2T, W3T);
    fused_mlp<<<BSZ / MB, NT, 0, stream>>>(states, action,
                                           W1T, b1, W2T, b2, W3T, b3,
                                           lng, lnb, out);
}